// Round 4
// baseline (284.545 us; speedup 1.0000x reference)
//
#include <hip/hip_runtime.h>
#include <hip/hip_fp16.h>
#include <hip/hip_bf16.h>

typedef short bf16x8 __attribute__((ext_vector_type(8)));
typedef float f32x4 __attribute__((ext_vector_type(4)));

// ---------------------------------------------------------------------------
// K1: per-node log_map (tangent projection, bf16 output) + gate softmax
// one wave per node; lane handles dims {2l, 2l+1}
// ---------------------------------------------------------------------------
__global__ __launch_bounds__(256) void k_tangent_gate(
    const float* __restrict__ x, const float* __restrict__ Wg,
    const float* __restrict__ bg, __hip_bfloat16* __restrict__ xtb,
    float* __restrict__ gate, int N) {
  int wid = (blockIdx.x * blockDim.x + threadIdx.x) >> 6;
  int lane = threadIdx.x & 63;
  if (wid >= N) return;

  const float* xr = x + (size_t)wid * 128;
  float2 xv = *(const float2*)(xr + lane * 2);
  xv.x = fminf(fmaxf(xv.x, -10000.f), 10000.f);
  xv.y = fminf(fmaxf(xv.y, -10000.f), 10000.f);

  // pseudo-Riemannian x_sq = -x0^2 + sum_{d>=1} x_d^2
  float p = xv.x * xv.x + xv.y * xv.y;
  if (lane == 0) p -= 2.f * xv.x * xv.x;
  #pragma unroll
  for (int s = 32; s; s >>= 1) p += __shfl_xor(p, s);
  float x0 = __shfl(xv.x, 0);

  // scalar pipeline in fp64 (cancellation near acosh(1+eps))
  double xsq = (double)p;
  double denom = sqrt(fmax(fabs(xsq), 1e-12));
  double cosd = fmax((double)x0 / denom, 1.0 + 1e-6);
  double dist = acosh(cosd);
  double sind = fmax(sqrt(cosd * cosd - 1.0), 1e-12);
  double coef = dist / sind;

  float2 o;
  o.x = (float)(coef * ((lane == 0) ? 2.0 * (double)xv.x : (double)xv.x));
  o.y = (float)(coef * (double)xv.y);
  __hip_bfloat162 hb = __float22bfloat162_rn(make_float2(o.x, o.y));
  *(__hip_bfloat162*)(xtb + (size_t)wid * 128 + lane * 2) = hb;

  // gate = softmax(o @ Wg + bg)
  const float4 w0 = *(const float4*)(Wg + (size_t)(lane * 2) * 4);
  const float4 w1 = *(const float4*)(Wg + (size_t)(lane * 2 + 1) * 4);
  float g0 = o.x * w0.x + o.y * w1.x;
  float g1 = o.x * w0.y + o.y * w1.y;
  float g2 = o.x * w0.z + o.y * w1.z;
  float g3 = o.x * w0.w + o.y * w1.w;
  #pragma unroll
  for (int s = 32; s; s >>= 1) {
    g0 += __shfl_xor(g0, s); g1 += __shfl_xor(g1, s);
    g2 += __shfl_xor(g2, s); g3 += __shfl_xor(g3, s);
  }
  g0 += bg[0]; g1 += bg[1]; g2 += bg[2]; g3 += bg[3];
  float m = fmaxf(fmaxf(g0, g1), fmaxf(g2, g3));
  float e0 = expf(g0 - m), e1 = expf(g1 - m), e2 = expf(g2 - m), e3 = expf(g3 - m);
  float z = e0 + e1 + e2 + e3;
  if (lane == 0)
    *(float4*)(gate + (size_t)wid * 4) = make_float4(e0 / z, e1 / z, e2 / z, e3 / z);
}

// ---------------------------------------------------------------------------
// K1b: transpose W_per [128,512] f32 -> Wt [512,128] bf16 (K-contiguous rows)
// ---------------------------------------------------------------------------
__global__ __launch_bounds__(256) void k_wt(const float* __restrict__ Wp,
                                            __hip_bfloat16* __restrict__ Wt) {
  int idx = blockIdx.x * 256 + threadIdx.x;   // 65536 total
  int n = idx >> 7, k = idx & 127;
  Wt[idx] = __float2bfloat16(Wp[(size_t)k * 512 + n]);
}

// ---------------------------------------------------------------------------
// K2: u_hat via bf16 MFMA.  u[n,d] = sum_p gate[n,p]*(xt[n,:]@W[:,p,d]+bp[p,d])
// 64 rows/block, 4 waves. C/D: col=lane&15, row=(lane>>4)*4+reg. Output f16.
// ---------------------------------------------------------------------------
#define BM 64
__global__ __launch_bounds__(256) void k_uhat_mfma(
    const short* __restrict__ xtb, const float* __restrict__ gate,
    const short* __restrict__ Wt, const float* __restrict__ bp,
    __half* __restrict__ uh, int N) {
  __shared__ short sA[BM][136];
  __shared__ short sB[128][136];
  int tid = threadIdx.x;
  int lane = tid & 63;
  int w = tid >> 6;
  int m0 = blockIdx.x * BM;

  #pragma unroll
  for (int it = 0; it < 4; ++it) {
    int idx = it * 256 + tid;
    int r = idx >> 4, c = idx & 15;
    int4 v = make_int4(0, 0, 0, 0);
    if (m0 + r < N) v = *(const int4*)(xtb + (((size_t)(m0 + r)) << 7) + c * 8);
    *(int4*)(&sA[r][c * 8]) = v;
  }

  int mr = w * 16;
  int ri = lane & 15;
  int kg = lane >> 4;
  int rbase = m0 + mr + kg * 4;

  float fin[8][4];
  #pragma unroll
  for (int nt = 0; nt < 8; ++nt)
    #pragma unroll
    for (int q = 0; q < 4; ++q) fin[nt][q] = 0.f;

  for (int p = 0; p < 4; ++p) {
    __syncthreads();
    #pragma unroll
    for (int it = 0; it < 8; ++it) {
      int idx = it * 256 + tid;
      int r = idx >> 4, c = idx & 15;
      int4 v = *(const int4*)(Wt + (((size_t)p * 128 + r) << 7) + c * 8);
      *(int4*)(&sB[r][c * 8]) = v;
    }
    __syncthreads();

    bf16x8 af[4];
    #pragma unroll
    for (int ks = 0; ks < 4; ++ks)
      af[ks] = *(const bf16x8*)(&sA[mr + ri][ks * 32 + kg * 8]);

    #pragma unroll
    for (int nt = 0; nt < 8; ++nt) {
      f32x4 acc = {0.f, 0.f, 0.f, 0.f};
      #pragma unroll
      for (int ks = 0; ks < 4; ++ks) {
        bf16x8 bf = *(const bf16x8*)(&sB[nt * 16 + ri][ks * 32 + kg * 8]);
        acc = __builtin_amdgcn_mfma_f32_16x16x32_bf16(af[ks], bf, acc, 0, 0, 0);
      }
      float bpv = bp[p * 128 + nt * 16 + ri];
      #pragma unroll
      for (int q = 0; q < 4; ++q) {
        int rm = rbase + q;
        float g = (rm < N) ? gate[(size_t)rm * 4 + p] : 0.f;
        fin[nt][q] += g * (acc[q] + bpv);
      }
    }
  }
  #pragma unroll
  for (int nt = 0; nt < 8; ++nt) {
    int cn = nt * 16 + ri;
    #pragma unroll
    for (int q = 0; q < 4; ++q) {
      int rm = rbase + q;
      if (rm < N) uh[(size_t)rm * 128 + cn] = __float2half_rn(fin[nt][q]);
    }
  }
}

// ---------------------------------------------------------------------------
// CSR-by-col: histogram + hierarchical scan + scatter
// ---------------------------------------------------------------------------
__global__ void k_hist(const int* __restrict__ col, int* __restrict__ deg, int E) {
  int e = blockIdx.x * blockDim.x + threadIdx.x;
  if (e < E) atomicAdd(&deg[col[e]], 1);
}

#define SCH 1024
__global__ __launch_bounds__(256) void k_bsum(const int* __restrict__ deg,
                                              int* __restrict__ bsum, int N) {
  __shared__ int ws[4];
  int tid = threadIdx.x;
  int base = blockIdx.x * SCH;
  int v = 0;
  #pragma unroll
  for (int k = 0; k < 4; k++) {
    int i = base + k * 256 + tid;
    if (i < N) v += deg[i];
  }
  #pragma unroll
  for (int s = 32; s; s >>= 1) v += __shfl_xor(v, s);
  if ((tid & 63) == 0) ws[tid >> 6] = v;
  __syncthreads();
  if (tid == 0) bsum[blockIdx.x] = ws[0] + ws[1] + ws[2] + ws[3];
}

__global__ __launch_bounds__(64) void k_bscan(const int* __restrict__ bsum,
                                              int* __restrict__ boff,
                                              int* __restrict__ off, int NB, int N) {
  int lane = threadIdx.x;
  int carry = 0;
  for (int base = 0; base < NB; base += 64) {
    int i = base + lane;
    int v = (i < NB) ? bsum[i] : 0;
    int sc = v;
    #pragma unroll
    for (int s = 1; s < 64; s <<= 1) {
      int t = __shfl_up(sc, s);
      if (lane >= s) sc += t;
    }
    if (i < NB) boff[i] = carry + sc - v;
    carry += __shfl(sc, 63);
  }
  if (lane == 0) off[N] = carry;
}

__global__ __launch_bounds__(256) void k_scan2(const int* __restrict__ deg,
                                               const int* __restrict__ boff,
                                               int* __restrict__ off,
                                               int* __restrict__ cur, int N) {
  __shared__ int wtot[4];
  int tid = threadIdx.x;
  int lane = tid & 63;
  int base = blockIdx.x * SCH + tid * 4;
  int v[4];
  #pragma unroll
  for (int k = 0; k < 4; k++) v[k] = (base + k < N) ? deg[base + k] : 0;
  int tsum = v[0] + v[1] + v[2] + v[3];
  int sc = tsum;
  #pragma unroll
  for (int s = 1; s < 64; s <<= 1) {
    int t = __shfl_up(sc, s);
    if (lane >= s) sc += t;
  }
  if (lane == 63) wtot[tid >> 6] = sc;
  __syncthreads();
  int w = tid >> 6;
  int woff = 0;
  if (w > 0) woff += wtot[0];
  if (w > 1) woff += wtot[1];
  if (w > 2) woff += wtot[2];
  int pre = boff[blockIdx.x] + woff + sc - tsum;
  #pragma unroll
  for (int k = 0; k < 4; k++) {
    int i = base + k;
    if (i < N) { off[i] = pre; cur[i] = pre; }
    pre += v[k];
  }
}

__global__ void k_scatter(const int* __restrict__ row, const int* __restrict__ col,
                          int* __restrict__ cur, int* __restrict__ csr_row, int E) {
  int e = blockIdx.x * blockDim.x + threadIdx.x;
  if (e < E) {
    int p = atomicAdd(&cur[col[e]], 1);
    csr_row[p] = row[e];
  }
}

// ---------------------------------------------------------------------------
// K6: fused 3-iteration routing + squash + exp_map.
// Register-resident u (no LDS), 4 nodes per 256-thread block, one wave/node.
// Gathers fully unrolled (CAP=32) with uniform guards -> all loads in flight.
// Logits b: lane i holds b_i; broadcast via shfl. No barriers anywhere.
// ---------------------------------------------------------------------------
#define CAP 32
__global__ __launch_bounds__(256, 4) void k_route(
    const __half* __restrict__ uh, const float* __restrict__ bias,
    const int* __restrict__ csr_off, const int* __restrict__ csr_row,
    float* __restrict__ bg_ws, float* __restrict__ out, int N) {
  int lane = threadIdx.x & 63;
  int j = blockIdx.x * 4 + (threadIdx.x >> 6);
  if (j >= N) return;
  int o0 = csr_off[j];
  int deg = csr_off[j + 1] - o0;
  int d0 = lane * 2;

  if (deg == 0) {
    *(float2*)(out + (size_t)j * 128 + d0) =
        make_float2((lane == 0) ? 1.f : 0.f, 0.f);
    return;
  }

  float2 bia = *(const float2*)(bias + d0);
  float s0 = 0.f, s1 = 0.f;

  if (deg <= CAP) {
    const __half2* uh2 = (const __half2*)uh;
    int myrow = (lane < deg) ? csr_row[o0 + lane] : 0;
    __half2 u[CAP];

    // issue all gathers back-to-back (independent dest regs)
    #pragma unroll
    for (int i = 0; i < CAP; ++i) {
      if (i < deg) {
        int rr = __shfl(myrow, i);
        u[i] = uh2[(((size_t)rr) << 6) + lane];
      }
    }
    // round-0: uniform coefficients (b=0 -> c=1/deg)
    float a0 = 0.f, a1 = 0.f;
    #pragma unroll
    for (int i = 0; i < CAP; ++i) {
      if (i < deg) {
        float2 uf = __half22float2(u[i]);
        a0 += uf.x; a1 += uf.y;
      }
    }
    float invd = 1.f / (float)deg;
    s0 = a0 * invd + bia.x;
    s1 = a1 * invd + bia.y;
    {
      float ns = s0 * s0 + s1 * s1;
      #pragma unroll
      for (int s = 32; s; s >>= 1) ns += __shfl_xor(ns, s);
      float scale = (ns / (1.f + ns)) * rsqrtf(ns + 1e-9f);
      s0 *= scale; s1 *= scale;
    }

    float b = 0.f;   // lane i holds b_i (i < deg)
    #pragma unroll
    for (int r = 0; r < 2; ++r) {
      // b_i += dot(s, u_i): 8 independent butterfly chains per batch
      #pragma unroll
      for (int i0 = 0; i0 < CAP; i0 += 8) {
        if (i0 < deg) {
          float p[8];
          #pragma unroll
          for (int k = 0; k < 8; ++k) {
            int i = i0 + k;
            float2 uf = (i < deg) ? __half22float2(u[i]) : make_float2(0.f, 0.f);
            p[k] = s0 * uf.x + s1 * uf.y;
          }
          #pragma unroll
          for (int k = 0; k < 8; ++k)
            #pragma unroll
            for (int s = 32; s; s >>= 1) p[k] += __shfl_xor(p[k], s);
          float pv = p[0];
          #pragma unroll
          for (int k = 1; k < 8; ++k) pv = (lane == i0 + k) ? p[k] : pv;
          if (lane >= i0 && lane < i0 + 8) b += pv;
        }
      }
      // softmax-weighted sum (no max-shift; |b| small). lane i -> e_i
      float eb = __expf(b);
      float z = 0.f;
      a0 = 0.f; a1 = 0.f;
      #pragma unroll
      for (int i = 0; i < CAP; ++i) {
        if (i < deg) {
          float e = __shfl(eb, i);
          float2 uf = __half22float2(u[i]);
          z += e;
          a0 = fmaf(e, uf.x, a0);
          a1 = fmaf(e, uf.y, a1);
        }
      }
      float invz = 1.f / z;
      s0 = a0 * invz + bia.x;
      s1 = a1 * invz + bia.y;
      float ns = s0 * s0 + s1 * s1;
      #pragma unroll
      for (int s = 32; s; s >>= 1) ns += __shfl_xor(ns, s);
      float scale = (ns / (1.f + ns)) * rsqrtf(ns + 1e-9f);
      s0 *= scale; s1 *= scale;
    }
  } else {
    // fallback (deg > CAP, ~never for Poisson(10)): L2-coherent atomics,
    // per-wave only, no barriers.
    float* b = bg_ws + o0;
    const __half2* uh2 = (const __half2*)uh;
    for (int i = lane; i < deg; i += 64) atomicExch(&b[i], 0.f);
    asm volatile("s_waitcnt vmcnt(0)" ::: "memory");

    for (int r = 0; r < 3; ++r) {
      float mx = -3.4e38f;
      for (int i = lane; i < deg; i += 64)
        mx = fmaxf(mx, atomicAdd(&b[i], 0.f));
      #pragma unroll
      for (int s = 32; s; s >>= 1) mx = fmaxf(mx, __shfl_xor(mx, s));
      float z = 0.f;
      for (int i = lane; i < deg; i += 64) z += expf(atomicAdd(&b[i], 0.f) - mx);
      #pragma unroll
      for (int s = 32; s; s >>= 1) z += __shfl_xor(z, s);
      float invz = 1.f / z;

      s0 = 0.f; s1 = 0.f;
      for (int i = 0; i < deg; ++i) {
        float c = expf(atomicAdd(&b[i], 0.f) - mx) * invz;
        int rr = csr_row[o0 + i];
        float2 uf = __half22float2(uh2[(((size_t)rr) << 6) + lane]);
        s0 = fmaf(c, uf.x, s0);
        s1 = fmaf(c, uf.y, s1);
      }
      s0 += bia.x; s1 += bia.y;

      float ns = s0 * s0 + s1 * s1;
      #pragma unroll
      for (int s = 32; s; s >>= 1) ns += __shfl_xor(ns, s);
      float scale = (ns / (1.f + ns)) * rsqrtf(ns + 1e-9f);
      s0 *= scale; s1 *= scale;

      if (r < 2) {
        for (int i = 0; i < deg; ++i) {
          int rr = csr_row[o0 + i];
          float2 uf = __half22float2(uh2[(((size_t)rr) << 6) + lane]);
          float pp = s0 * uf.x + s1 * uf.y;
          #pragma unroll
          for (int s = 32; s; s >>= 1) pp += __shfl_xor(pp, s);
          if (lane == 0) atomicAdd(&b[i], pp);
        }
        asm volatile("s_waitcnt vmcnt(0)" ::: "memory");
      }
    }
  }

  // exp_map(s, ref)
  float pn = s0 * s0 + s1 * s1;
  if (lane == 0) pn -= 2.f * s0 * s0;
  #pragma unroll
  for (int s = 32; s; s >>= 1) pn += __shfl_xor(pn, s);
  float vn = fminf(sqrtf(fabsf(pn) + 1e-12f), 10.f);
  float sh = sinhf(vn) / vn;
  float ov0 = sh * s0 + ((lane == 0) ? coshf(vn) : 0.f);
  float ov1 = sh * s1;
  *(float2*)(out + (size_t)j * 128 + d0) = make_float2(ov0, ov1);
}

// ---------------------------------------------------------------------------
extern "C" void kernel_launch(void* const* d_in, const int* in_sizes, int n_in,
                              void* d_out, int out_size, void* d_ws, size_t ws_size,
                              hipStream_t stream) {
  const float* x    = (const float*)d_in[0];
  const int*   ei   = (const int*)d_in[1];
  const float* Wp   = (const float*)d_in[2];
  const float* bp   = (const float*)d_in[3];
  const float* Wg   = (const float*)d_in[4];
  const float* bg   = (const float*)d_in[5];
  const float* bias = (const float*)d_in[6];
  float* out = (float*)d_out;

  int N = in_sizes[0] / 128;
  int E = in_sizes[1] / 2;
  const int* row = ei;
  const int* col = ei + E;
  int NB = (N + SCH - 1) / SCH;

  __hip_bfloat16* xtb = (__hip_bfloat16*)d_ws;               // N*128 bf16
  __half* uhh = (__half*)(xtb + (size_t)N * 128);            // N*128 f16
  float* gate = (float*)(uhh + (size_t)N * 128);             // N*4 f32
  __hip_bfloat16* Wt = (__hip_bfloat16*)(gate + (size_t)N * 4); // 512*128 bf16
  float* bws = (float*)(Wt + 512 * 128);                     // E f32
  int* deg = (int*)(bws + E);
  int* off = deg + N;
  int* cur = off + N + 1;
  int* csr_row = cur + N;
  int* bsum = csr_row + E;
  int* boff = bsum + NB;

  hipMemsetAsync(deg, 0, (size_t)N * sizeof(int), stream);
  k_tangent_gate<<<(N + 3) / 4, 256, 0, stream>>>(x, Wg, bg, xtb, gate, N);
  k_wt<<<256, 256, 0, stream>>>(Wp, Wt);
  k_uhat_mfma<<<(N + BM - 1) / BM, 256, 0, stream>>>(
      (const short*)xtb, gate, (const short*)Wt, bp, uhh, N);
  k_hist<<<(E + 255) / 256, 256, 0, stream>>>(col, deg, E);
  k_bsum<<<NB, 256, 0, stream>>>(deg, bsum, N);
  k_bscan<<<1, 64, 0, stream>>>(bsum, boff, off, NB, N);
  k_scan2<<<NB, 256, 0, stream>>>(deg, boff, off, cur, N);
  k_scatter<<<(E + 255) / 256, 256, 0, stream>>>(row, col, cur, csr_row, E);
  k_route<<<(N + 3) / 4, 256, 0, stream>>>(uhh, bias, off, csr_row, bws, out, N);
}